// Round 1
// baseline (989.637 us; speedup 1.0000x reference)
//
#include <hip/hip_runtime.h>

// GraphSAGE fused pipeline, f32, MI355X.
// Phases: CSR build (count/scan/fill) -> agg1 -> gemm1(relu) -> agg2 -> gemm2 -> classifier.
// conv2 GEMM writes the embedding region of d_out in place (row-local read-before-write).

#define FEATS 128

static __device__ __forceinline__ float4 ld4(const float* p) {
    return *reinterpret_cast<const float4*>(p);
}

// ---------------- CSR build ----------------

__global__ __launch_bounds__(256)
void count_kernel(const int* __restrict__ dst, int* __restrict__ cnt, int E) {
    int i = blockIdx.x * 256 + threadIdx.x;
    if (i < E) atomicAdd(&cnt[dst[i]], 1);
}

// single-block exclusive scan of cnt[0..N) -> offs[0..N], plus a working copy in cur[].
__global__ __launch_bounds__(1024)
void scan_kernel(const int* __restrict__ cnt, int* __restrict__ offs,
                 int* __restrict__ cur, int N) {
    __shared__ int sums[1024];
    const int tid = threadIdx.x;
    const int chunk = (N + 1023) >> 10;
    int s = tid * chunk; if (s > N) s = N;
    int e = s + chunk;   if (e > N) e = N;
    int a = 0;
    for (int i = s; i < e; i++) a += cnt[i];
    sums[tid] = a;
    __syncthreads();
    for (int off = 1; off < 1024; off <<= 1) {
        int v = (tid >= off) ? sums[tid - off] : 0;
        __syncthreads();
        sums[tid] += v;
        __syncthreads();
    }
    int base = (tid == 0) ? 0 : sums[tid - 1];
    for (int i = s; i < e; i++) { offs[i] = base; cur[i] = base; base += cnt[i]; }
    if (tid == 1023) offs[N] = sums[1023];
}

__global__ __launch_bounds__(256)
void fill_kernel(const int* __restrict__ src, const int* __restrict__ dst,
                 int* __restrict__ cur, int* __restrict__ ssrc, int E) {
    int i = blockIdx.x * 256 + threadIdx.x;
    if (i < E) {
        int p = atomicAdd(&cur[dst[i]], 1);
        ssrc[p] = src[i];
    }
}

// ---------------- neighbor mean aggregation (pull, no atomics) ----------------
// One wave (64 lanes) per node; lane handles 2 floats (float2 -> 8B/lane, 512B/edge coalesced).
__global__ __launch_bounds__(256)
void agg_kernel(const float2* __restrict__ x2, const int* __restrict__ ssrc,
                const int* __restrict__ offs, float2* __restrict__ out2, int N) {
    const int g = blockIdx.x * 4 + (threadIdx.x >> 6);   // node
    const int lane = threadIdx.x & 63;
    if (g >= N) return;
    const int beg = offs[g], end = offs[g + 1];
    float ax = 0.f, ay = 0.f;
    int e = beg;
    // 2-way unroll to overlap the dependent (index -> feature) load chains
    for (; e + 1 < end; e += 2) {
        int s0 = ssrc[e], s1 = ssrc[e + 1];
        float2 v0 = x2[(size_t)s0 * 64 + lane];
        float2 v1 = x2[(size_t)s1 * 64 + lane];
        ax += v0.x + v1.x; ay += v0.y + v1.y;
    }
    if (e < end) {
        int s0 = ssrc[e];
        float2 v0 = x2[(size_t)s0 * 64 + lane];
        ax += v0.x; ay += v0.y;
    }
    const int d = end - beg;
    const float inv = 1.0f / (float)(d > 1 ? d : 1);
    float2 o; o.x = ax * inv; o.y = ay * inv;
    out2[(size_t)g * 64 + lane] = o;
}

// ---------------- fused SAGE linear: C = act(A1 @ Wl^T + bias + A2 @ Wr^T) ----------------
// Treated as one GEMM with K=256 (concat A1|A2, Wl|Wr). BM=64, BN=128, BK=16.
// 256 threads: 8 thread-rows x 32 thread-cols, 8x4 micro-tile each.
// Per k-step: 2x ds_read_b128 (A) + 1x ds_read_b128 (B) for 32 FMAs -> compute-bound.
__global__ __launch_bounds__(256)
void sage_gemm(const float* __restrict__ A1, const float* __restrict__ A2,
               const float* __restrict__ Wl, const float* __restrict__ Wr,
               const float* __restrict__ bias, float* __restrict__ C,
               int M, int do_relu) {
    __shared__ float As[16][68];    // [k][row], pad 68 -> conflict-free writes, aligned b128 reads
    __shared__ float Bs[16][128];   // [k][col] = W[col][k] (transposed at stage time)
    const int tid = threadIdx.x;
    const int tr = tid >> 5;            // 0..7  -> rows tr*8..tr*8+7
    const int tc = tid & 31;            // 0..31 -> cols tc*4..tc*4+3
    const int row0 = blockIdx.x * 64;
    const int lr = tid >> 2;            // staging: row 0..63
    const int lk = (tid & 3) << 2;      // staging: k 0,4,8,12
    const int bcol = tid >> 1;          // staging: col 0..127
    const int bkq = (tid & 1) << 3;     // staging: k 0 or 8

    float acc[8][4];
    #pragma unroll
    for (int m = 0; m < 8; m++)
        #pragma unroll
        for (int n = 0; n < 4; n++) acc[m][n] = 0.f;

    for (int kk = 0; kk < 16; kk++) {
        const float* Asrc = (kk < 8) ? A1 : A2;
        const float* Wsrc = (kk < 8) ? Wl : Wr;
        const int k0 = (kk & 7) << 4;

        // stage A tile (64 rows x 16 k), transpose to [k][row]
        const int gr = row0 + lr;
        float4 av = make_float4(0.f, 0.f, 0.f, 0.f);
        if (gr < M) av = ld4(Asrc + (size_t)gr * FEATS + k0 + lk);
        As[lk + 0][lr] = av.x; As[lk + 1][lr] = av.y;
        As[lk + 2][lr] = av.z; As[lk + 3][lr] = av.w;

        // stage B tile (16 k x 128 cols), transpose W[col][k] -> Bs[k][col]
        float4 b0 = ld4(Wsrc + (size_t)bcol * FEATS + k0 + bkq);
        float4 b1 = ld4(Wsrc + (size_t)bcol * FEATS + k0 + bkq + 4);
        Bs[bkq + 0][bcol] = b0.x; Bs[bkq + 1][bcol] = b0.y;
        Bs[bkq + 2][bcol] = b0.z; Bs[bkq + 3][bcol] = b0.w;
        Bs[bkq + 4][bcol] = b1.x; Bs[bkq + 5][bcol] = b1.y;
        Bs[bkq + 6][bcol] = b1.z; Bs[bkq + 7][bcol] = b1.w;
        __syncthreads();

        #pragma unroll
        for (int k = 0; k < 16; k++) {
            float4 a0 = *(const float4*)&As[k][tr * 8];
            float4 a1 = *(const float4*)&As[k][tr * 8 + 4];
            float4 bv = *(const float4*)&Bs[k][tc * 4];
            float am[8] = {a0.x, a0.y, a0.z, a0.w, a1.x, a1.y, a1.z, a1.w};
            float bn[4] = {bv.x, bv.y, bv.z, bv.w};
            #pragma unroll
            for (int m = 0; m < 8; m++)
                #pragma unroll
                for (int n = 0; n < 4; n++)
                    acc[m][n] += am[m] * bn[n];
        }
        __syncthreads();
    }

    float4 bv = ld4(bias + tc * 4);
    float bb[4] = {bv.x, bv.y, bv.z, bv.w};
    #pragma unroll
    for (int m = 0; m < 8; m++) {
        const int r = row0 + tr * 8 + m;
        if (r < M) {
            float4 o;
            o.x = acc[m][0] + bb[0]; o.y = acc[m][1] + bb[1];
            o.z = acc[m][2] + bb[2]; o.w = acc[m][3] + bb[3];
            if (do_relu) {
                o.x = fmaxf(o.x, 0.f); o.y = fmaxf(o.y, 0.f);
                o.z = fmaxf(o.z, 0.f); o.w = fmaxf(o.w, 0.f);
            }
            *reinterpret_cast<float4*>(C + (size_t)r * FEATS + tc * 4) = o;
        }
    }
}

// ---------------- classifier + softmax + argmax ----------------
// thread = row; Wc (20KB) staged in LDS, read wave-uniform (broadcast, conflict-free).
__global__ __launch_bounds__(256)
void classifier_kernel(const float* __restrict__ emb, const float* __restrict__ Wc,
                       const float* __restrict__ bc, float* __restrict__ logits,
                       float* __restrict__ soft, float* __restrict__ hard, int N) {
    __shared__ float Ws[40 * 128];
    __shared__ float bs[40];
    for (int i = threadIdx.x; i < 40 * 128; i += 256) Ws[i] = Wc[i];
    if (threadIdx.x < 40) bs[threadIdx.x] = bc[threadIdx.x];
    __syncthreads();
    const int row = blockIdx.x * 256 + threadIdx.x;
    if (row >= N) return;

    float acc[40];
    #pragma unroll
    for (int f = 0; f < 40; f++) acc[f] = 0.f;

    const float* erow = emb + (size_t)row * FEATS;
    for (int c = 0; c < 8; c++) {            // k chunks of 16 (not unrolled: keeps icache sane)
        float4 r0 = ld4(erow + c * 16 + 0);
        float4 r1 = ld4(erow + c * 16 + 4);
        float4 r2 = ld4(erow + c * 16 + 8);
        float4 r3 = ld4(erow + c * 16 + 12);
        #pragma unroll
        for (int f = 0; f < 40; f++) {       // unrolled: acc[] stays in registers
            const float* w = &Ws[f * 128 + c * 16];
            float4 w0 = ld4(w), w1 = ld4(w + 4), w2 = ld4(w + 8), w3 = ld4(w + 12);
            acc[f] += r0.x * w0.x + r0.y * w0.y + r0.z * w0.z + r0.w * w0.w
                    + r1.x * w1.x + r1.y * w1.y + r1.z * w1.z + r1.w * w1.w
                    + r2.x * w2.x + r2.y * w2.y + r2.z * w2.z + r2.w * w2.w
                    + r3.x * w3.x + r3.y * w3.y + r3.z * w3.z + r3.w * w3.w;
        }
    }
    #pragma unroll
    for (int f = 0; f < 40; f++) acc[f] += bs[f];

    float m = acc[0]; int idx = 0;
    #pragma unroll
    for (int f = 1; f < 40; f++) { if (acc[f] > m) { m = acc[f]; idx = f; } }

    float* lrow = logits + (size_t)row * 40;
    #pragma unroll
    for (int f = 0; f < 40; f++) lrow[f] = acc[f];   // write logits, then reuse acc for exp

    float sum = 0.f;
    #pragma unroll
    for (int f = 0; f < 40; f++) { acc[f] = __expf(acc[f] - m); sum += acc[f]; }
    const float inv = 1.0f / sum;
    float* srow = soft + (size_t)row * 40;
    #pragma unroll
    for (int f = 0; f < 40; f++) srow[f] = acc[f] * inv;
    hard[row] = (float)idx;
}

// ---------------- launch ----------------

static inline size_t align16(size_t x) { return (x + 15) & ~(size_t)15; }

extern "C" void kernel_launch(void* const* d_in, const int* in_sizes, int n_in,
                              void* d_out, int out_size, void* d_ws, size_t ws_size,
                              hipStream_t stream) {
    const float* x   = (const float*)d_in[0];
    const int*   ei  = (const int*)d_in[1];
    const float* W1l = (const float*)d_in[2];
    const float* b1  = (const float*)d_in[3];
    const float* W1r = (const float*)d_in[4];
    const float* W2l = (const float*)d_in[5];
    const float* b2  = (const float*)d_in[6];
    const float* W2r = (const float*)d_in[7];
    const float* Wc  = (const float*)d_in[8];
    const float* bc  = (const float*)d_in[9];

    const int N = in_sizes[0] / FEATS;
    const int E = in_sizes[1] / 2;
    const int* src = ei;          // edge_index[0]
    const int* dst = ei + E;      // edge_index[1]

    // workspace layout
    char* ws = (char*)d_ws;
    size_t oCnt  = 0;
    size_t oOffs = oCnt  + align16((size_t)N * 4);
    size_t oCur  = oOffs + align16((size_t)(N + 1) * 4);
    size_t oSsrc = oCur  + align16((size_t)N * 4);
    size_t oAgg  = oSsrc + align16((size_t)E * 4);
    int*   cnt    = (int*)(ws + oCnt);
    int*   offs   = (int*)(ws + oOffs);
    int*   cur    = (int*)(ws + oCur);
    int*   ssrc   = (int*)(ws + oSsrc);
    float* aggbuf = (float*)(ws + oAgg);      // N x 128 f32

    // output layout: logits | embedding | soft_label | hard_label
    float* out    = (float*)d_out;
    float* logits = out;
    float* emb    = out + (size_t)N * 40;
    float* soft   = emb + (size_t)N * FEATS;
    float* hard   = soft + (size_t)N * 40;

    const int gridE = (E + 255) / 256;
    const int gridAgg = (N + 3) / 4;
    const int gridGemm = (N + 63) / 64;
    const int gridRow = (N + 255) / 256;

    hipMemsetAsync(cnt, 0, (size_t)N * 4, stream);
    count_kernel<<<gridE, 256, 0, stream>>>(dst, cnt, E);
    scan_kernel<<<1, 1024, 0, stream>>>(cnt, offs, cur, N);
    fill_kernel<<<gridE, 256, 0, stream>>>(src, dst, cur, ssrc, E);

    // conv1: h1 = relu(agg(x) @ W1l^T + b1 + x @ W1r^T)  -> stored in emb region
    agg_kernel<<<gridAgg, 256, 0, stream>>>((const float2*)x, ssrc, offs, (float2*)aggbuf, N);
    sage_gemm<<<gridGemm, 256, 0, stream>>>(aggbuf, x, W1l, W1r, b1, emb, N, 1);

    // conv2: emb = agg(h1) @ W2l^T + b2 + h1 @ W2r^T   (in-place on emb region)
    agg_kernel<<<gridAgg, 256, 0, stream>>>((const float2*)emb, ssrc, offs, (float2*)aggbuf, N);
    sage_gemm<<<gridGemm, 256, 0, stream>>>(aggbuf, emb, W2l, W2r, b2, emb, N, 0);

    // classifier + softmax + argmax
    classifier_kernel<<<gridRow, 256, 0, stream>>>(emb, Wc, bc, logits, soft, hard, N);
}

// Round 2
// 829.822 us; speedup vs baseline: 1.1926x; 1.1926x over previous
//
#include <hip/hip_runtime.h>

// GraphSAGE fused pipeline, f32, MI355X.
// R2: hierarchical scan (was 233us single-block serial), 128x128 GEMM tile w/ 8x8 micro.

#define FEATS 128
#define SCAN_CHUNK 4096

static __device__ __forceinline__ float4 ld4(const float* p) {
    return *reinterpret_cast<const float4*>(p);
}

// ---------------- CSR build ----------------

__global__ __launch_bounds__(256)
void count_kernel(const int* __restrict__ dst, int* __restrict__ cnt, int E) {
    int i = blockIdx.x * 256 + threadIdx.x;
    if (i < E) atomicAdd(&cnt[dst[i]], 1);
}

// pass 1: per-block (4096-elt) partial sums, coalesced strided loads
__global__ __launch_bounds__(256)
void scan_partial(const int* __restrict__ cnt, int* __restrict__ part, int N) {
    __shared__ int red[256];
    const int base = blockIdx.x * SCAN_CHUNK;
    int sum = 0;
    for (int i = threadIdx.x; i < SCAN_CHUNK; i += 256) {
        int idx = base + i;
        sum += (idx < N) ? cnt[idx] : 0;
    }
    red[threadIdx.x] = sum;
    __syncthreads();
    for (int off = 128; off > 0; off >>= 1) {
        if (threadIdx.x < off) red[threadIdx.x] += red[threadIdx.x + off];
        __syncthreads();
    }
    if (threadIdx.x == 0) part[blockIdx.x] = red[0];
}

// pass 2: single-block scan of the partials (nb <= 1024), total -> *totalp (= offs[N])
__global__ __launch_bounds__(1024)
void scan_part2(int* __restrict__ part, int nb, int* __restrict__ totalp) {
    __shared__ int s[1024];
    const int tid = threadIdx.x;
    s[tid] = (tid < nb) ? part[tid] : 0;
    __syncthreads();
    for (int off = 1; off < 1024; off <<= 1) {
        int t = (tid >= off) ? s[tid - off] : 0;
        __syncthreads();
        s[tid] += t;
        __syncthreads();
    }
    if (tid < nb) part[tid] = (tid == 0) ? 0 : s[tid - 1];   // exclusive block offsets
    if (tid == 0) *totalp = s[1023];                          // grand total (zeros padded)
}

// pass 3: per-block exclusive scan (each thread owns 16 consecutive), add block offset
__global__ __launch_bounds__(256)
void scan_final(const int* __restrict__ cnt, const int* __restrict__ part,
                int* __restrict__ offs, int* __restrict__ cur, int N) {
    __shared__ int tsum[256];
    const int tid = threadIdx.x;
    const int myb = blockIdx.x * SCAN_CHUNK + tid * 16;
    int v[16];
    int s = 0;
    #pragma unroll
    for (int j = 0; j < 16; j++) {
        int idx = myb + j;
        int c = (idx < N) ? cnt[idx] : 0;
        v[j] = s; s += c;
    }
    tsum[tid] = s;
    __syncthreads();
    for (int off = 1; off < 256; off <<= 1) {
        int t = (tid >= off) ? tsum[tid - off] : 0;
        __syncthreads();
        tsum[tid] += t;
        __syncthreads();
    }
    const int base = part[blockIdx.x] + ((tid == 0) ? 0 : tsum[tid - 1]);
    #pragma unroll
    for (int j = 0; j < 16; j++) {
        int idx = myb + j;
        if (idx < N) { int o = base + v[j]; offs[idx] = o; cur[idx] = o; }
    }
}

__global__ __launch_bounds__(256)
void fill_kernel(const int* __restrict__ src, const int* __restrict__ dst,
                 int* __restrict__ cur, int* __restrict__ ssrc, int E) {
    int i = blockIdx.x * 256 + threadIdx.x;
    if (i < E) {
        int p = atomicAdd(&cur[dst[i]], 1);
        ssrc[p] = src[i];
    }
}

// ---------------- neighbor mean aggregation (pull, no atomics) ----------------
// One wave (64 lanes) per node; lane handles 2 floats (float2 -> 8B/lane, 512B/edge coalesced).
__global__ __launch_bounds__(256)
void agg_kernel(const float2* __restrict__ x2, const int* __restrict__ ssrc,
                const int* __restrict__ offs, float2* __restrict__ out2, int N) {
    const int g = blockIdx.x * 4 + (threadIdx.x >> 6);   // node
    const int lane = threadIdx.x & 63;
    if (g >= N) return;
    const int beg = offs[g], end = offs[g + 1];
    float ax = 0.f, ay = 0.f;
    int e = beg;
    for (; e + 1 < end; e += 2) {
        int s0 = ssrc[e], s1 = ssrc[e + 1];
        float2 v0 = x2[(size_t)s0 * 64 + lane];
        float2 v1 = x2[(size_t)s1 * 64 + lane];
        ax += v0.x + v1.x; ay += v0.y + v1.y;
    }
    if (e < end) {
        int s0 = ssrc[e];
        float2 v0 = x2[(size_t)s0 * 64 + lane];
        ax += v0.x; ay += v0.y;
    }
    const int d = end - beg;
    const float inv = 1.0f / (float)(d > 1 ? d : 1);
    float2 o; o.x = ax * inv; o.y = ay * inv;
    out2[(size_t)g * 64 + lane] = o;
}

// ---------------- fused SAGE linear: C = act(A1 @ Wl^T + bias + A2 @ Wr^T) ----------------
// One GEMM with K=256 (concat A1|A2, Wl|Wr). BM=128, BN=128, BK=16.
// 256 threads as 16x16; each thread an 8x8 micro-tile.
// Per k-step: 2x b128 A (wave-broadcast, conflict-free) + 2x b128 B for 64 FMAs -> VALU-bound.
__global__ __launch_bounds__(256)
void sage_gemm(const float* __restrict__ A1, const float* __restrict__ A2,
               const float* __restrict__ Wl, const float* __restrict__ Wr,
               const float* __restrict__ bias, float* __restrict__ C,
               int M, int do_relu) {
    __shared__ float As[16][132];   // [k][row], pad -> staging writes 2-way (free)
    __shared__ float Bs[16][132];   // [k][col] = W[col][k]
    const int tid = threadIdx.x;
    const int tr = tid >> 4;            // 0..15 -> rows tr*8..tr*8+7
    const int tc = tid & 15;            // 0..15 -> cols tc*8..tc*8+7
    const int row0 = blockIdx.x * 128;
    const int lr = tid >> 2;            // A staging: rows lr, lr+64
    const int lk = (tid & 3) << 2;      // A staging: k lk..lk+3
    const int bcol = tid >> 1;          // B staging: col 0..127
    const int bkq = (tid & 1) << 3;     // B staging: k 0 or 8

    float acc[8][8];
    #pragma unroll
    for (int m = 0; m < 8; m++)
        #pragma unroll
        for (int n = 0; n < 8; n++) acc[m][n] = 0.f;

    for (int kk = 0; kk < 16; kk++) {
        const float* Asrc = (kk < 8) ? A1 : A2;
        const float* Wsrc = (kk < 8) ? Wl : Wr;
        const int k0 = (kk & 7) << 4;

        // stage A tile (128 rows x 16 k), transpose to [k][row]; 2 rows/thread
        #pragma unroll
        for (int h = 0; h < 2; h++) {
            const int r = lr + h * 64;
            const int gr = row0 + r;
            float4 av = make_float4(0.f, 0.f, 0.f, 0.f);
            if (gr < M) av = ld4(Asrc + (size_t)gr * FEATS + k0 + lk);
            As[lk + 0][r] = av.x; As[lk + 1][r] = av.y;
            As[lk + 2][r] = av.z; As[lk + 3][r] = av.w;
        }

        // stage B tile (16 k x 128 cols), transpose W[col][k] -> Bs[k][col]
        float4 b0 = ld4(Wsrc + (size_t)bcol * FEATS + k0 + bkq);
        float4 b1 = ld4(Wsrc + (size_t)bcol * FEATS + k0 + bkq + 4);
        Bs[bkq + 0][bcol] = b0.x; Bs[bkq + 1][bcol] = b0.y;
        Bs[bkq + 2][bcol] = b0.z; Bs[bkq + 3][bcol] = b0.w;
        Bs[bkq + 4][bcol] = b1.x; Bs[bkq + 5][bcol] = b1.y;
        Bs[bkq + 6][bcol] = b1.z; Bs[bkq + 7][bcol] = b1.w;
        __syncthreads();

        #pragma unroll
        for (int k = 0; k < 16; k++) {
            float4 a0 = *(const float4*)&As[k][tr * 8];
            float4 a1 = *(const float4*)&As[k][tr * 8 + 4];
            float4 b0v = *(const float4*)&Bs[k][tc * 8];
            float4 b1v = *(const float4*)&Bs[k][tc * 8 + 4];
            float am[8] = {a0.x, a0.y, a0.z, a0.w, a1.x, a1.y, a1.z, a1.w};
            float bn[8] = {b0v.x, b0v.y, b0v.z, b0v.w, b1v.x, b1v.y, b1v.z, b1v.w};
            #pragma unroll
            for (int m = 0; m < 8; m++)
                #pragma unroll
                for (int n = 0; n < 8; n++)
                    acc[m][n] += am[m] * bn[n];
        }
        __syncthreads();
    }

    float4 bv0 = ld4(bias + tc * 8);
    float4 bv1 = ld4(bias + tc * 8 + 4);
    float bb[8] = {bv0.x, bv0.y, bv0.z, bv0.w, bv1.x, bv1.y, bv1.z, bv1.w};
    #pragma unroll
    for (int m = 0; m < 8; m++) {
        const int r = row0 + tr * 8 + m;
        if (r < M) {
            float o[8];
            #pragma unroll
            for (int n = 0; n < 8; n++) {
                o[n] = acc[m][n] + bb[n];
                if (do_relu) o[n] = fmaxf(o[n], 0.f);
            }
            float* cp = C + (size_t)r * FEATS + tc * 8;
            *reinterpret_cast<float4*>(cp)     = make_float4(o[0], o[1], o[2], o[3]);
            *reinterpret_cast<float4*>(cp + 4) = make_float4(o[4], o[5], o[6], o[7]);
        }
    }
}

// ---------------- classifier + softmax + argmax ----------------
__global__ __launch_bounds__(256)
void classifier_kernel(const float* __restrict__ emb, const float* __restrict__ Wc,
                       const float* __restrict__ bc, float* __restrict__ logits,
                       float* __restrict__ soft, float* __restrict__ hard, int N) {
    __shared__ float Ws[40 * 128];
    __shared__ float bs[40];
    for (int i = threadIdx.x; i < 40 * 128; i += 256) Ws[i] = Wc[i];
    if (threadIdx.x < 40) bs[threadIdx.x] = bc[threadIdx.x];
    __syncthreads();
    const int row = blockIdx.x * 256 + threadIdx.x;
    if (row >= N) return;

    float acc[40];
    #pragma unroll
    for (int f = 0; f < 40; f++) acc[f] = 0.f;

    const float* erow = emb + (size_t)row * FEATS;
    for (int c = 0; c < 8; c++) {
        float4 r0 = ld4(erow + c * 16 + 0);
        float4 r1 = ld4(erow + c * 16 + 4);
        float4 r2 = ld4(erow + c * 16 + 8);
        float4 r3 = ld4(erow + c * 16 + 12);
        #pragma unroll
        for (int f = 0; f < 40; f++) {
            const float* w = &Ws[f * 128 + c * 16];
            float4 w0 = ld4(w), w1 = ld4(w + 4), w2 = ld4(w + 8), w3 = ld4(w + 12);
            acc[f] += r0.x * w0.x + r0.y * w0.y + r0.z * w0.z + r0.w * w0.w
                    + r1.x * w1.x + r1.y * w1.y + r1.z * w1.z + r1.w * w1.w
                    + r2.x * w2.x + r2.y * w2.y + r2.z * w2.z + r2.w * w2.w
                    + r3.x * w3.x + r3.y * w3.y + r3.z * w3.z + r3.w * w3.w;
        }
    }
    #pragma unroll
    for (int f = 0; f < 40; f++) acc[f] += bs[f];

    float m = acc[0]; int idx = 0;
    #pragma unroll
    for (int f = 1; f < 40; f++) { if (acc[f] > m) { m = acc[f]; idx = f; } }

    float* lrow = logits + (size_t)row * 40;
    #pragma unroll
    for (int f = 0; f < 40; f++) lrow[f] = acc[f];

    float sum = 0.f;
    #pragma unroll
    for (int f = 0; f < 40; f++) { acc[f] = __expf(acc[f] - m); sum += acc[f]; }
    const float inv = 1.0f / sum;
    float* srow = soft + (size_t)row * 40;
    #pragma unroll
    for (int f = 0; f < 40; f++) srow[f] = acc[f] * inv;
    hard[row] = (float)idx;
}

// ---------------- launch ----------------

static inline size_t align16(size_t x) { return (x + 15) & ~(size_t)15; }

extern "C" void kernel_launch(void* const* d_in, const int* in_sizes, int n_in,
                              void* d_out, int out_size, void* d_ws, size_t ws_size,
                              hipStream_t stream) {
    const float* x   = (const float*)d_in[0];
    const int*   ei  = (const int*)d_in[1];
    const float* W1l = (const float*)d_in[2];
    const float* b1  = (const float*)d_in[3];
    const float* W1r = (const float*)d_in[4];
    const float* W2l = (const float*)d_in[5];
    const float* b2  = (const float*)d_in[6];
    const float* W2r = (const float*)d_in[7];
    const float* Wc  = (const float*)d_in[8];
    const float* bc  = (const float*)d_in[9];

    const int N = in_sizes[0] / FEATS;
    const int E = in_sizes[1] / 2;
    const int* src = ei;          // edge_index[0]
    const int* dst = ei + E;      // edge_index[1]
    const int nb = (N + SCAN_CHUNK - 1) / SCAN_CHUNK;

    // workspace layout
    char* ws = (char*)d_ws;
    size_t oCnt  = 0;
    size_t oOffs = oCnt  + align16((size_t)N * 4);
    size_t oCur  = oOffs + align16((size_t)(N + 1) * 4);
    size_t oPart = oCur  + align16((size_t)N * 4);
    size_t oSsrc = oPart + align16((size_t)nb * 4);
    size_t oAgg  = oSsrc + align16((size_t)E * 4);
    int*   cnt    = (int*)(ws + oCnt);
    int*   offs   = (int*)(ws + oOffs);
    int*   cur    = (int*)(ws + oCur);
    int*   part   = (int*)(ws + oPart);
    int*   ssrc   = (int*)(ws + oSsrc);
    float* aggbuf = (float*)(ws + oAgg);      // N x 128 f32

    // output layout: logits | embedding | soft_label | hard_label
    float* out    = (float*)d_out;
    float* logits = out;
    float* emb    = out + (size_t)N * 40;
    float* soft   = emb + (size_t)N * FEATS;
    float* hard   = soft + (size_t)N * 40;

    const int gridE = (E + 255) / 256;
    const int gridAgg = (N + 3) / 4;
    const int gridGemm = (N + 127) / 128;
    const int gridRow = (N + 255) / 256;

    hipMemsetAsync(cnt, 0, (size_t)N * 4, stream);
    count_kernel<<<gridE, 256, 0, stream>>>(dst, cnt, E);
    scan_partial<<<nb, 256, 0, stream>>>(cnt, part, N);
    scan_part2<<<1, 1024, 0, stream>>>(part, nb, offs + N);
    scan_final<<<nb, 256, 0, stream>>>(cnt, part, offs, cur, N);
    fill_kernel<<<gridE, 256, 0, stream>>>(src, dst, cur, ssrc, E);

    // conv1: h1 = relu(agg(x) @ W1l^T + b1 + x @ W1r^T)  -> stored in emb region
    agg_kernel<<<gridAgg, 256, 0, stream>>>((const float2*)x, ssrc, offs, (float2*)aggbuf, N);
    sage_gemm<<<gridGemm, 256, 0, stream>>>(aggbuf, x, W1l, W1r, b1, emb, N, 1);

    // conv2: emb = agg(h1) @ W2l^T + b2 + h1 @ W2r^T   (in-place on emb region, row-local)
    agg_kernel<<<gridAgg, 256, 0, stream>>>((const float2*)emb, ssrc, offs, (float2*)aggbuf, N);
    sage_gemm<<<gridGemm, 256, 0, stream>>>(aggbuf, emb, W2l, W2r, b2, emb, N, 0);

    // classifier + softmax + argmax
    classifier_kernel<<<gridRow, 256, 0, stream>>>(emb, Wc, bc, logits, soft, hard, N);
}

// Round 4
// 697.718 us; speedup vs baseline: 1.4184x; 1.1893x over previous
//
#include <hip/hip_runtime.h>

// GraphSAGE fused pipeline, f32, MI355X.
// R3 (resubmit; prior round hit GPUAcquisitionTimeout): atomic-free CSR build via
// LDS radix partition (global atomicAdd on MI355X write-throughs 64B/op to HBM ->
// count+fill were ~250us at 0.3% VALUBusy in R2's profile).

#define FEATS 128
#define SCAN_CHUNK 4096
#define BSHIFT 9                 // 512 nodes per bucket
#define BSIZE  (1 << BSHIFT)
#define MAXNB  256               // supports N <= 131072
#define EPB    8192              // edges per hist/scatter block

static __device__ __forceinline__ float4 ld4(const float* p) {
    return *reinterpret_cast<const float4*>(p);
}

// ---------------- CSR build: radix partition, LDS atomics only ----------------

// pass A: per-block bucket histogram -> bhist[bucket * nblkA + blk]
__global__ __launch_bounds__(256)
void hist_kernel(const int* __restrict__ dst, int* __restrict__ bhist,
                 int E, int NB, int nblkA) {
    __shared__ int hist[MAXNB];
    const int tid = threadIdx.x, blk = blockIdx.x;
    for (int t = tid; t < MAXNB; t += 256) hist[t] = 0;
    __syncthreads();
    const int e0 = blk * EPB;
    const int e1 = min(E, e0 + EPB);
    for (int i = e0 + tid; i < e1; i += 256)
        atomicAdd(&hist[dst[i] >> BSHIFT], 1);
    __syncthreads();
    for (int t = tid; t < NB; t += 256) bhist[t * nblkA + blk] = hist[t];
}

// scan pass 1: per-chunk partial sums
__global__ __launch_bounds__(256)
void scan_partial(const int* __restrict__ cnt, int* __restrict__ part, int N) {
    __shared__ int red[256];
    const int base = blockIdx.x * SCAN_CHUNK;
    int sum = 0;
    for (int i = threadIdx.x; i < SCAN_CHUNK; i += 256) {
        int idx = base + i;
        sum += (idx < N) ? cnt[idx] : 0;
    }
    red[threadIdx.x] = sum;
    __syncthreads();
    for (int off = 128; off > 0; off >>= 1) {
        if (threadIdx.x < off) red[threadIdx.x] += red[threadIdx.x + off];
        __syncthreads();
    }
    if (threadIdx.x == 0) part[blockIdx.x] = red[0];
}

// scan pass 2: single-block scan of partials (nb <= 1024); total -> *totalp
__global__ __launch_bounds__(1024)
void scan_part2(int* __restrict__ part, int nb, int* __restrict__ totalp) {
    __shared__ int s[1024];
    const int tid = threadIdx.x;
    s[tid] = (tid < nb) ? part[tid] : 0;
    __syncthreads();
    for (int off = 1; off < 1024; off <<= 1) {
        int t = (tid >= off) ? s[tid - off] : 0;
        __syncthreads();
        s[tid] += t;
        __syncthreads();
    }
    if (tid < nb) part[tid] = (tid == 0) ? 0 : s[tid - 1];
    if (tid == 0) *totalp = s[1023];
}

// scan pass 3: per-chunk exclusive scan + block offset -> out[]
__global__ __launch_bounds__(256)
void scan_out(const int* __restrict__ cnt, const int* __restrict__ part,
              int* __restrict__ out, int Ntot) {
    __shared__ int tsum[256];
    const int tid = threadIdx.x;
    const int myb = blockIdx.x * SCAN_CHUNK + tid * 16;
    int v[16];
    int s = 0;
    #pragma unroll
    for (int j = 0; j < 16; j++) {
        int idx = myb + j;
        int c = (idx < Ntot) ? cnt[idx] : 0;
        v[j] = s; s += c;
    }
    tsum[tid] = s;
    __syncthreads();
    for (int off = 1; off < 256; off <<= 1) {
        int t = (tid >= off) ? tsum[tid - off] : 0;
        __syncthreads();
        tsum[tid] += t;
        __syncthreads();
    }
    const int base = part[blockIdx.x] + ((tid == 0) ? 0 : tsum[tid - 1]);
    #pragma unroll
    for (int j = 0; j < 16; j++) {
        int idx = myb + j;
        if (idx < Ntot) out[idx] = base + v[j];
    }
}

// pass C: scatter edges into bucket-grouped packed array. Slot ranges per
// (bucket, block) are disjoint by construction -> LDS cursors, no global atomics.
__global__ __launch_bounds__(256)
void scatter_kernel(const int* __restrict__ src, const int* __restrict__ dst,
                    const int* __restrict__ scanT, int* __restrict__ packed,
                    int E, int NB, int nblkA) {
    __shared__ int cur[MAXNB];
    const int tid = threadIdx.x, blk = blockIdx.x;
    for (int t = tid; t < NB; t += 256) cur[t] = scanT[t * nblkA + blk];
    __syncthreads();
    const int e0 = blk * EPB;
    const int e1 = min(E, e0 + EPB);
    for (int i = e0 + tid; i < e1; i += 256) {
        int d = dst[i], s = src[i];
        int bkt = d >> BSHIFT;
        int slot = atomicAdd(&cur[bkt], 1);
        packed[slot] = ((d & (BSIZE - 1)) << 17) | s;   // 9b local-dst | 17b src
    }
}

// pass D: one block per bucket. LDS histogram over 512 local nodes, LDS scan,
// write global offs, then fill ssrc with LDS cursors.
__global__ __launch_bounds__(256)
void bucket_csr(const int* __restrict__ packed, const int* __restrict__ scanT,
                int* __restrict__ offs, int* __restrict__ ssrc,
                int N, int E, int NB, int nblkA) {
    __shared__ int lcnt[BSIZE];
    __shared__ int lofs[BSIZE];
    __shared__ int s[256];
    const int tid = threadIdx.x, b = blockIdx.x;
    const int base_b = scanT[b * nblkA];
    const int end_b = (b == NB - 1) ? E : scanT[(b + 1) * nblkA];
    const int n0 = b << BSHIFT;
    const int nn = min(BSIZE, N - n0);

    lcnt[tid] = 0; lcnt[tid + 256] = 0;
    __syncthreads();
    for (int i = base_b + tid; i < end_b; i += 256)
        atomicAdd(&lcnt[packed[i] >> 17], 1);
    __syncthreads();

    // exclusive scan of lcnt[0..511]; thread owns elems 2t, 2t+1
    const int a0 = lcnt[2 * tid], a1 = lcnt[2 * tid + 1];
    s[tid] = a0 + a1;
    __syncthreads();
    for (int off = 1; off < 256; off <<= 1) {
        int t = (tid >= off) ? s[tid - off] : 0;
        __syncthreads();
        s[tid] += t;
        __syncthreads();
    }
    const int ebase = (tid == 0) ? 0 : s[tid - 1];
    lofs[2 * tid] = ebase;
    lofs[2 * tid + 1] = ebase + a0;
    __syncthreads();

    for (int j = tid; j < nn; j += 256) offs[n0 + j] = base_b + lofs[j];
    if (b == NB - 1 && tid == 0) offs[N] = E;
    __syncthreads();

    for (int i = base_b + tid; i < end_b; i += 256) {
        int c = packed[i];
        int slot = atomicAdd(&lofs[c >> 17], 1);
        ssrc[base_b + slot] = c & 0x1FFFF;
    }
}

// ---------------- neighbor mean aggregation (pull, no atomics) ----------------
__global__ __launch_bounds__(256)
void agg_kernel(const float2* __restrict__ x2, const int* __restrict__ ssrc,
                const int* __restrict__ offs, float2* __restrict__ out2, int N) {
    const int g = blockIdx.x * 4 + (threadIdx.x >> 6);   // node
    const int lane = threadIdx.x & 63;
    if (g >= N) return;
    const int beg = offs[g], end = offs[g + 1];
    float ax = 0.f, ay = 0.f;
    int e = beg;
    for (; e + 1 < end; e += 2) {
        int s0 = ssrc[e], s1 = ssrc[e + 1];
        float2 v0 = x2[(size_t)s0 * 64 + lane];
        float2 v1 = x2[(size_t)s1 * 64 + lane];
        ax += v0.x + v1.x; ay += v0.y + v1.y;
    }
    if (e < end) {
        int s0 = ssrc[e];
        float2 v0 = x2[(size_t)s0 * 64 + lane];
        ax += v0.x; ay += v0.y;
    }
    const int d = end - beg;
    const float inv = 1.0f / (float)(d > 1 ? d : 1);
    float2 o; o.x = ax * inv; o.y = ay * inv;
    out2[(size_t)g * 64 + lane] = o;
}

// ---------------- fused SAGE linear: C = act(A1 @ Wl^T + bias + A2 @ Wr^T) ----------------
__global__ __launch_bounds__(256)
void sage_gemm(const float* __restrict__ A1, const float* __restrict__ A2,
               const float* __restrict__ Wl, const float* __restrict__ Wr,
               const float* __restrict__ bias, float* __restrict__ C,
               int M, int do_relu) {
    __shared__ float As[16][132];
    __shared__ float Bs[16][132];
    const int tid = threadIdx.x;
    const int tr = tid >> 4;
    const int tc = tid & 15;
    const int row0 = blockIdx.x * 128;
    const int lr = tid >> 2;
    const int lk = (tid & 3) << 2;
    const int bcol = tid >> 1;
    const int bkq = (tid & 1) << 3;

    float acc[8][8];
    #pragma unroll
    for (int m = 0; m < 8; m++)
        #pragma unroll
        for (int n = 0; n < 8; n++) acc[m][n] = 0.f;

    for (int kk = 0; kk < 16; kk++) {
        const float* Asrc = (kk < 8) ? A1 : A2;
        const float* Wsrc = (kk < 8) ? Wl : Wr;
        const int k0 = (kk & 7) << 4;

        #pragma unroll
        for (int h = 0; h < 2; h++) {
            const int r = lr + h * 64;
            const int gr = row0 + r;
            float4 av = make_float4(0.f, 0.f, 0.f, 0.f);
            if (gr < M) av = ld4(Asrc + (size_t)gr * FEATS + k0 + lk);
            As[lk + 0][r] = av.x; As[lk + 1][r] = av.y;
            As[lk + 2][r] = av.z; As[lk + 3][r] = av.w;
        }

        float4 b0 = ld4(Wsrc + (size_t)bcol * FEATS + k0 + bkq);
        float4 b1 = ld4(Wsrc + (size_t)bcol * FEATS + k0 + bkq + 4);
        Bs[bkq + 0][bcol] = b0.x; Bs[bkq + 1][bcol] = b0.y;
        Bs[bkq + 2][bcol] = b0.z; Bs[bkq + 3][bcol] = b0.w;
        Bs[bkq + 4][bcol] = b1.x; Bs[bkq + 5][bcol] = b1.y;
        Bs[bkq + 6][bcol] = b1.z; Bs[bkq + 7][bcol] = b1.w;
        __syncthreads();

        #pragma unroll
        for (int k = 0; k < 16; k++) {
            float4 a0 = *(const float4*)&As[k][tr * 8];
            float4 a1 = *(const float4*)&As[k][tr * 8 + 4];
            float4 b0v = *(const float4*)&Bs[k][tc * 8];
            float4 b1v = *(const float4*)&Bs[k][tc * 8 + 4];
            float am[8] = {a0.x, a0.y, a0.z, a0.w, a1.x, a1.y, a1.z, a1.w};
            float bn[8] = {b0v.x, b0v.y, b0v.z, b0v.w, b1v.x, b1v.y, b1v.z, b1v.w};
            #pragma unroll
            for (int m = 0; m < 8; m++)
                #pragma unroll
                for (int n = 0; n < 8; n++)
                    acc[m][n] += am[m] * bn[n];
        }
        __syncthreads();
    }

    float4 bv0 = ld4(bias + tc * 8);
    float4 bv1 = ld4(bias + tc * 8 + 4);
    float bb[8] = {bv0.x, bv0.y, bv0.z, bv0.w, bv1.x, bv1.y, bv1.z, bv1.w};
    #pragma unroll
    for (int m = 0; m < 8; m++) {
        const int r = row0 + tr * 8 + m;
        if (r < M) {
            float o[8];
            #pragma unroll
            for (int n = 0; n < 8; n++) {
                o[n] = acc[m][n] + bb[n];
                if (do_relu) o[n] = fmaxf(o[n], 0.f);
            }
            float* cp = C + (size_t)r * FEATS + tc * 8;
            *reinterpret_cast<float4*>(cp)     = make_float4(o[0], o[1], o[2], o[3]);
            *reinterpret_cast<float4*>(cp + 4) = make_float4(o[4], o[5], o[6], o[7]);
        }
    }
}

// ---------------- classifier + softmax + argmax ----------------
__global__ __launch_bounds__(256)
void classifier_kernel(const float* __restrict__ emb, const float* __restrict__ Wc,
                       const float* __restrict__ bc, float* __restrict__ logits,
                       float* __restrict__ soft, float* __restrict__ hard, int N) {
    __shared__ float Ws[40 * 128];
    __shared__ float bs[40];
    for (int i = threadIdx.x; i < 40 * 128; i += 256) Ws[i] = Wc[i];
    if (threadIdx.x < 40) bs[threadIdx.x] = bc[threadIdx.x];
    __syncthreads();
    const int row = blockIdx.x * 256 + threadIdx.x;
    if (row >= N) return;

    float acc[40];
    #pragma unroll
    for (int f = 0; f < 40; f++) acc[f] = 0.f;

    const float* erow = emb + (size_t)row * FEATS;
    for (int c = 0; c < 8; c++) {
        float4 r0 = ld4(erow + c * 16 + 0);
        float4 r1 = ld4(erow + c * 16 + 4);
        float4 r2 = ld4(erow + c * 16 + 8);
        float4 r3 = ld4(erow + c * 16 + 12);
        #pragma unroll
        for (int f = 0; f < 40; f++) {
            const float* w = &Ws[f * 128 + c * 16];
            float4 w0 = ld4(w), w1 = ld4(w + 4), w2 = ld4(w + 8), w3 = ld4(w + 12);
            acc[f] += r0.x * w0.x + r0.y * w0.y + r0.z * w0.z + r0.w * w0.w
                    + r1.x * w1.x + r1.y * w1.y + r1.z * w1.z + r1.w * w1.w
                    + r2.x * w2.x + r2.y * w2.y + r2.z * w2.z + r2.w * w2.w
                    + r3.x * w3.x + r3.y * w3.y + r3.z * w3.z + r3.w * w3.w;
        }
    }
    #pragma unroll
    for (int f = 0; f < 40; f++) acc[f] += bs[f];

    float m = acc[0]; int idx = 0;
    #pragma unroll
    for (int f = 1; f < 40; f++) { if (acc[f] > m) { m = acc[f]; idx = f; } }

    float* lrow = logits + (size_t)row * 40;
    #pragma unroll
    for (int f = 0; f < 40; f++) lrow[f] = acc[f];

    float sum = 0.f;
    #pragma unroll
    for (int f = 0; f < 40; f++) { acc[f] = __expf(acc[f] - m); sum += acc[f]; }
    const float inv = 1.0f / sum;
    float* srow = soft + (size_t)row * 40;
    #pragma unroll
    for (int f = 0; f < 40; f++) srow[f] = acc[f] * inv;
    hard[row] = (float)idx;
}

// ---------------- launch ----------------

static inline size_t align16(size_t x) { return (x + 15) & ~(size_t)15; }

extern "C" void kernel_launch(void* const* d_in, const int* in_sizes, int n_in,
                              void* d_out, int out_size, void* d_ws, size_t ws_size,
                              hipStream_t stream) {
    const float* x   = (const float*)d_in[0];
    const int*   ei  = (const int*)d_in[1];
    const float* W1l = (const float*)d_in[2];
    const float* b1  = (const float*)d_in[3];
    const float* W1r = (const float*)d_in[4];
    const float* W2l = (const float*)d_in[5];
    const float* b2  = (const float*)d_in[6];
    const float* W2r = (const float*)d_in[7];
    const float* Wc  = (const float*)d_in[8];
    const float* bc  = (const float*)d_in[9];

    const int N = in_sizes[0] / FEATS;
    const int E = in_sizes[1] / 2;
    const int* src = ei;          // edge_index[0]
    const int* dst = ei + E;      // edge_index[1]

    const int NB    = (N + BSIZE - 1) >> BSHIFT;     // buckets (<= MAXNB)
    const int nblkA = (E + EPB - 1) / EPB;           // hist/scatter blocks
    const int T     = NB * nblkA;                    // scan length
    const int nb2   = (T + SCAN_CHUNK - 1) / SCAN_CHUNK;

    // workspace layout (packed aliases the head of aggbuf; dead before agg runs)
    char* ws = (char*)d_ws;
    size_t oScanT = 0;
    size_t oBhist = oScanT + align16((size_t)(T + 1) * 4);
    size_t oPart  = oBhist + align16((size_t)T * 4);
    size_t oOffs  = oPart  + align16((size_t)1024 * 4);
    size_t oSsrc  = oOffs  + align16((size_t)(N + 1) * 4);
    size_t oAgg   = oSsrc  + align16((size_t)E * 4);
    int*   scanT  = (int*)(ws + oScanT);
    int*   bhist  = (int*)(ws + oBhist);
    int*   part   = (int*)(ws + oPart);
    int*   offs   = (int*)(ws + oOffs);
    int*   ssrc   = (int*)(ws + oSsrc);
    float* aggbuf = (float*)(ws + oAgg);      // N x 128 f32
    int*   packed = (int*)(ws + oAgg);        // E ints, aliases aggbuf

    // output layout: logits | embedding | soft_label | hard_label
    float* out    = (float*)d_out;
    float* logits = out;
    float* emb    = out + (size_t)N * 40;
    float* soft   = emb + (size_t)N * FEATS;
    float* hard   = soft + (size_t)N * 40;

    const int gridAgg = (N + 3) / 4;
    const int gridGemm = (N + 127) / 128;
    const int gridRow = (N + 255) / 256;

    // CSR build (LDS atomics only)
    hist_kernel<<<nblkA, 256, 0, stream>>>(dst, bhist, E, NB, nblkA);
    scan_partial<<<nb2, 256, 0, stream>>>(bhist, part, T);
    scan_part2<<<1, 1024, 0, stream>>>(part, nb2, scanT + T);
    scan_out<<<nb2, 256, 0, stream>>>(bhist, part, scanT, T);
    scatter_kernel<<<nblkA, 256, 0, stream>>>(src, dst, scanT, packed, E, NB, nblkA);
    bucket_csr<<<NB, 256, 0, stream>>>(packed, scanT, offs, ssrc, N, E, NB, nblkA);

    // conv1: h1 = relu(agg(x) @ W1l^T + b1 + x @ W1r^T)  -> emb region
    agg_kernel<<<gridAgg, 256, 0, stream>>>((const float2*)x, ssrc, offs, (float2*)aggbuf, N);
    sage_gemm<<<gridGemm, 256, 0, stream>>>(aggbuf, x, W1l, W1r, b1, emb, N, 1);

    // conv2: emb = agg(h1) @ W2l^T + b2 + h1 @ W2r^T   (in-place, row-local)
    agg_kernel<<<gridAgg, 256, 0, stream>>>((const float2*)emb, ssrc, offs, (float2*)aggbuf, N);
    sage_gemm<<<gridGemm, 256, 0, stream>>>(aggbuf, emb, W2l, W2r, b2, emb, N, 0);

    // classifier + softmax + argmax
    classifier_kernel<<<gridRow, 256, 0, stream>>>(emb, Wc, bc, logits, soft, hard, N);
}